// Round 6
// baseline (353.714 us; speedup 1.0000x reference)
//
#include <hip/hip_runtime.h>
#include <hip/hip_bf16.h>

#define DD 128
#define TILE_BYTES 32768
#define WS_R_OFF   196608            // 6 tiles * 32768
#define WS_GB_OFF  199168            // + 640*4 (R')

typedef __attribute__((ext_vector_type(8))) short bf16x8;
typedef __attribute__((ext_vector_type(4))) float f32x4;

__device__ inline unsigned short f2bf(float f) {
  unsigned u = __float_as_uint(f);
  return (unsigned short)((u + 0x7fffu + ((u >> 16) & 1u)) >> 16);   // RNE
}

// async global->LDS, 16B per lane; LDS dest is wave-uniform base + lane*16
__device__ inline void async16(void* ldsp, const void* gp) {
  __builtin_amdgcn_global_load_lds(
      (const __attribute__((address_space(1))) void*)gp,
      (__attribute__((address_space(3))) void*)ldsp, 16, 0, 0);
}

// fill a 32 KB LDS weight slot from a pre-swizzled global image (256 threads)
__device__ inline void fill_w(char* slot, const char* src, int tid) {
  int w = tid >> 6, lane = tid & 63;
  #pragma unroll
  for (int i = 0; i < 8; ++i) {
    int ofs = ((i << 2) + w) << 10;            // 1 KB per wave-chunk
    async16(slot + ofs, src + ofs + lane * 16);
  }
}

// read a 16x32 bf16 MFMA fragment from a swizzled [rows][128] bf16 tile
__device__ inline bf16x8 ldfrag(const char* buf, int rowbase, int kk, int lane) {
  int row = rowbase + (lane & 15);
  int off = (row << 8) + (kk << 6) + (lane & 48);
  off ^= (row & 7) << 4;
  return *(const bf16x8*)(buf + off);
}

__device__ inline uint2 pack4(float v0, float v1, float v2, float v3) {
  return make_uint2((unsigned)f2bf(v0) | ((unsigned)f2bf(v1) << 16),
                    (unsigned)f2bf(v2) | ((unsigned)f2bf(v3) << 16));
}

// convert two prefetched float4 pairs into a bf16x8 fragment
__device__ inline bf16x8 cvt8(float4 f0, float4 f1) {
  bf16x8 r;
  r[0] = (short)f2bf(f0.x); r[1] = (short)f2bf(f0.y);
  r[2] = (short)f2bf(f0.z); r[3] = (short)f2bf(f0.w);
  r[4] = (short)f2bf(f1.x); r[5] = (short)f2bf(f1.y);
  r[6] = (short)f2bf(f1.z); r[7] = (short)f2bf(f1.w);
  return r;
}

#define MFMA(a, b, c) __builtin_amdgcn_mfma_f32_16x16x32_bf16((a), (b), (c), 0, 0, 0)

// ---------------- pre-kernel 1: weight tiles (bf16, [n][k], pre-swizzled) + R' ----------------
__global__ __launch_bounds__(256) void prep_weights(
    const float* __restrict__ W1, const float* __restrict__ W2,
    const float* __restrict__ a1W, const float* __restrict__ a2W,
    const float* __restrict__ geW,
    const float* __restrict__ r2e, const float* __restrict__ b1,
    unsigned short* __restrict__ wsw, float* __restrict__ Rp) {
  int gid = blockIdx.x * 256 + threadIdx.x;
  if (gid < 12288) {
    int tile = gid >> 11, idx = gid & 2047;
    int row = idx >> 4, slot = idx & 15;
    int slot2 = slot ^ (row & 7);              // inverse swizzle on source
    const float* W; int kb;
    switch (tile) {
      case 0:  W = W1;  kb = 0;   break;       // W1[:128]
      case 1:  W = W2;  kb = 0;   break;
      case 2:  W = a1W; kb = 0;   break;       // a1W[:128]
      case 3:  W = a2W; kb = 0;   break;
      case 4:  W = geW; kb = 0;   break;
      default: W = a1W; kb = 128; break;       // a1W[128:]
    }
    unsigned pk[4];
    #pragma unroll
    for (int p = 0; p < 4; ++p) {
      unsigned short lo = f2bf(W[(size_t)(kb + slot2 * 8 + 2 * p) * DD + row]);
      unsigned short hi = f2bf(W[(size_t)(kb + slot2 * 8 + 2 * p + 1) * DD + row]);
      pk[p] = (unsigned)lo | ((unsigned)hi << 16);
    }
    *(uint4*)(wsw + (size_t)tile * 16384 + (size_t)idx * 8) =
        make_uint4(pk[0], pk[1], pk[2], pk[3]);
  } else {
    // R'[5][128] = r2e @ W1[128:] + b1   (fp32 exact)
    int t = gid - 12288;
    for (int idx = t; idx < 640; idx += 256) {
      int r = idx >> 7, d = idx & 127;
      float s = b1[d];
      for (int k = 0; k < 128; ++k)
        s = fmaf(r2e[r * DD + k], W1[(size_t)(DD + k) * DD + d], s);
      Rp[idx] = s;
    }
  }
}

// ---------------- pre-kernel 2: gb[b][d] = a1b + relu(mean@geW+geb)@a1W[D:] ----------------
__global__ __launch_bounds__(256, 2) void prep_gb(
    const int* __restrict__ nodes, const float* __restrict__ u2e,
    const float* __restrict__ geb, const float* __restrict__ a1b,
    const char* __restrict__ tiles, float* __restrict__ gbv) {
  __shared__ char mean_s[4096];    // [16][128] bf16 swizzled
  __shared__ char g_s[4096];
  __shared__ char wslot[32768];
  __shared__ int nodes_s[128];
  int tid = threadIdx.x, w = tid >> 6, lane = tid & 63;
  int b0 = blockIdx.x * 16;
  if (tid < 128) nodes_s[tid] = nodes[b0 * 8 + tid];
  fill_w(wslot, tiles + 4 * TILE_BYTES, tid);      // geW
  __syncthreads();
  for (int idx = tid; idx < 2048; idx += 256) {
    int row = idx >> 7, d = idx & 127;
    float m = 0.f;
    #pragma unroll
    for (int j = 0; j < 8; ++j)
      m += u2e[(size_t)nodes_s[row * 8 + j] * DD + d];
    m *= 0.125f;
    int off = ((row << 8) + (d << 1)) ^ ((row & 7) << 4);
    *(unsigned short*)(mean_s + off) = f2bf(m);
  }
  __syncthreads();
  int cb = lane & 15, rb = (lane >> 4) << 2;
  f32x4 acc[2] = {(f32x4)(0.f), (f32x4)(0.f)};
  #pragma unroll
  for (int kk = 0; kk < 4; ++kk) {
    bf16x8 a = ldfrag(mean_s, 0, kk, lane);
    #pragma unroll
    for (int nf = 0; nf < 2; ++nf) {
      bf16x8 b = ldfrag(wslot, w * 32 + nf * 16, kk, lane);
      acc[nf] = MFMA(a, b, acc[nf]);
    }
  }
  __syncthreads();
  fill_w(wslot, tiles + 5 * TILE_BYTES, tid);      // a1W[128:]
  #pragma unroll
  for (int nf = 0; nf < 2; ++nf) {
    int col = w * 32 + nf * 16 + cb;
    float gb2 = geb[col];
    #pragma unroll
    for (int j = 0; j < 4; ++j) {
      int row = rb + j;
      float v = fmaxf(acc[nf][j] + gb2, 0.f);
      int off = ((row << 8) + (col << 1)) ^ ((row & 7) << 4);
      *(unsigned short*)(g_s + off) = f2bf(v);
    }
  }
  __syncthreads();
  acc[0] = (f32x4)(0.f); acc[1] = (f32x4)(0.f);
  #pragma unroll
  for (int kk = 0; kk < 4; ++kk) {
    bf16x8 a = ldfrag(g_s, 0, kk, lane);
    #pragma unroll
    for (int nf = 0; nf < 2; ++nf) {
      bf16x8 b = ldfrag(wslot, w * 32 + nf * 16, kk, lane);
      acc[nf] = MFMA(a, b, acc[nf]);
    }
  }
  #pragma unroll
  for (int nf = 0; nf < 2; ++nf) {
    int col = w * 32 + nf * 16 + cb;
    float bb = a1b[col];
    #pragma unroll
    for (int j = 0; j < 4; ++j)
      gbv[(size_t)(b0 + rb + j) * DD + col] = acc[nf][j] + bb;
  }
}

// 64f x 32l wave-tile GEMM over K=128 (A,B swizzled LDS tiles)
__device__ inline void gemmWX(f32x4 acc[8], const char* Wt, const char* Xt,
                              int mfw, int nlw, int lane) {
  #pragma unroll
  for (int kk = 0; kk < 4; ++kk) {
    bf16x8 bf0 = ldfrag(Xt, nlw * 32, kk, lane);
    bf16x8 bf1 = ldfrag(Xt, nlw * 32 + 16, kk, lane);
    #pragma unroll
    for (int mf = 0; mf < 4; ++mf) {
      bf16x8 a = ldfrag(Wt, mfw * 64 + mf * 16, kk, lane);
      acc[mf * 2]     = MFMA(a, bf0, acc[mf * 2]);
      acc[mf * 2 + 1] = MFMA(a, bf1, acc[mf * 2 + 1]);
    }
  }
}

// ---------------- main: weights-resident, 16 rows/block as 8 pairs, no launch_bounds ----------------
__global__ void main_kernel(
    const int* __restrict__ hu, const int* __restrict__ hr,
    const int* __restrict__ hlen,
    const float* __restrict__ v2e,
    const float* __restrict__ b2, const float* __restrict__ a2b,
    const float* __restrict__ a3W, const float* __restrict__ a3b,
    const char* __restrict__ tiles, const float* __restrict__ Rp,
    const float* __restrict__ gbv, float* __restrict__ out) {
  __shared__ char smem[133760];
  char*  W1s = smem;                 // 32768  (resident all kernel)
  char*  W2s = smem + 32768;         // 32768
  char*  A1s = smem + 65536;         // 32768
  char*  XA  = smem + 98304;         // 16384 (row A: x -> o -> a1 -> tail scratch)
  char*  XB  = smem + 114688;        // 16384 (row B)
  float* Rs  = (float*)(smem + 131072);  // [5][132] padded, 2640 B

  const int tid = threadIdx.x, lane = tid & 63;
  const int wv = tid >> 6;
  const int rowsel = wv >> 2;              // 0: row A, 1: row B
  const int w4 = wv & 3;
  const int mfw = w4 >> 1, nlw = w4 & 1;   // 64f x 32l wave tile
  const int cb = lane & 15, g = lane >> 4;
  char* X = rowsel ? XB : XA;

  // ---- prologue: resident weight fills (once per block) ----
  #pragma unroll
  for (int i = 0; i < 4; ++i) {
    int ofs = (i * 8 + wv) << 10;          // 8 waves x 4 sweeps x 1 KB
    async16(W1s + ofs, tiles + ofs + lane * 16);
    async16(W2s + ofs, tiles + TILE_BYTES + ofs + lane * 16);
    async16(A1s + ofs, tiles + 2 * TILE_BYTES + ofs + lane * 16);
  }
  for (int i = tid; i < 640; i += 512)
    Rs[(i >> 7) * 132 + (i & 127)] = Rp[i];

  // a2W fragments resident in registers (16 x bf16x8 = 64 VGPR)
  bf16x8 a2Wr[16];
  {
    const char* a2g = tiles + 3 * TILE_BYTES;
    #pragma unroll
    for (int mf = 0; mf < 4; ++mf)
      #pragma unroll
      for (int kk = 0; kk < 4; ++kk) {
        int row = mfw * 64 + mf * 16 + cb;
        int off = ((row << 8) + (kk << 6) + (lane & 48)) ^ ((row & 7) << 4);
        a2Wr[mf * 4 + kk] = *(const bf16x8*)(a2g + off);
      }
  }
  float4 a2br[4], a3wr[4];
  #pragma unroll
  for (int mf = 0; mf < 4; ++mf) {
    int f0 = mfw * 64 + mf * 16 + g * 4;
    a2br[mf] = *(const float4*)(a2b + f0);
    a3wr[mf] = *(const float4*)(a3W + f0);
  }
  const float a3bv = a3b[0];

  const int l0 = nlw * 32 + cb, l1 = l0 + 16;
  const int rbase = blockIdx.x * 16;
  int r = rbase + rowsel;
  int hu0 = hu[r * 64 + l0], hu1 = hu[r * 64 + l1];
  int hr0 = hr[r * 64 + l0], hr1 = hr[r * 64 + l1];

  // v2e prefetch for pair 0 (fp32, converted at use)
  float4 vpre[16];
  {
    const float* rp0 = v2e + (size_t)hu0 * DD;
    const float* rp1 = v2e + (size_t)hu1 * DD;
    #pragma unroll
    for (int kk = 0; kk < 4; ++kk) {
      const float4* q0 = (const float4*)(rp0 + (kk << 5) + (g << 3));
      const float4* q1 = (const float4*)(rp1 + (kk << 5) + (g << 3));
      vpre[kk * 4 + 0] = q0[0]; vpre[kk * 4 + 1] = q0[1];
      vpre[kk * 4 + 2] = q1[0]; vpre[kk * 4 + 3] = q1[1];
    }
  }
  __syncthreads();                         // weights + R' resident

  for (int p = 0; p < 8; ++p) {
    // next pair's history indices (issued early; used for v2e prefetch below)
    int hu0n = 0, hu1n = 0, hr0n = 0, hr1n = 0;
    if (p < 7) {
      int rn = r + 2;
      hu0n = hu[rn * 64 + l0]; hu1n = hu[rn * 64 + l1];
      hr0n = hr[rn * 64 + l0]; hr1n = hr[rn * 64 + l1];
    }

    f32x4 acc[8];
    #pragma unroll
    for (int i = 0; i < 8; ++i) acc[i] = (f32x4)(0.f);

    // ---- G1: x = e_uv @ W1[:128]; B from prefetched registers
    #pragma unroll
    for (int kk = 0; kk < 4; ++kk) {
      bf16x8 bf0 = cvt8(vpre[kk * 4 + 0], vpre[kk * 4 + 1]);
      bf16x8 bf1 = cvt8(vpre[kk * 4 + 2], vpre[kk * 4 + 3]);
      #pragma unroll
      for (int mf = 0; mf < 4; ++mf) {
        bf16x8 a = ldfrag(W1s, mfw * 64 + mf * 16, kk, lane);
        acc[mf * 2]     = MFMA(a, bf0, acc[mf * 2]);
        acc[mf * 2 + 1] = MFMA(a, bf1, acc[mf * 2 + 1]);
      }
    }
    // issue next pair's v2e prefetch (hides under G2..G4)
    if (p < 7) {
      const float* rp0 = v2e + (size_t)hu0n * DD;
      const float* rp1 = v2e + (size_t)hu1n * DD;
      #pragma unroll
      for (int kk = 0; kk < 4; ++kk) {
        const float4* q0 = (const float4*)(rp0 + (kk << 5) + (g << 3));
        const float4* q1 = (const float4*)(rp1 + (kk << 5) + (g << 3));
        vpre[kk * 4 + 0] = q0[0]; vpre[kk * 4 + 1] = q0[1];
        vpre[kk * 4 + 2] = q1[0]; vpre[kk * 4 + 3] = q1[1];
      }
    }
    // epi1: +R'[hr], relu -> X
    #pragma unroll
    for (int mf = 0; mf < 4; ++mf) {
      int f0 = mfw * 64 + mf * 16 + g * 4;
      float4 r0 = *(const float4*)(Rs + hr0 * 132 + f0);
      float4 r1 = *(const float4*)(Rs + hr1 * 132 + f0);
      f32x4 v0 = acc[mf * 2], v1 = acc[mf * 2 + 1];
      uint2 p0 = pack4(fmaxf(v0[0] + r0.x, 0.f), fmaxf(v0[1] + r0.y, 0.f),
                       fmaxf(v0[2] + r0.z, 0.f), fmaxf(v0[3] + r0.w, 0.f));
      uint2 p1 = pack4(fmaxf(v1[0] + r1.x, 0.f), fmaxf(v1[1] + r1.y, 0.f),
                       fmaxf(v1[2] + r1.z, 0.f), fmaxf(v1[3] + r1.w, 0.f));
      int o0 = ((l0 << 8) + (f0 << 1)) ^ ((l0 & 7) << 4);
      int o1 = ((l1 << 8) + (f0 << 1)) ^ ((l1 & 7) << 4);
      *(uint2*)(X + o0) = p0;
      *(uint2*)(X + o1) = p1;
    }
    __syncthreads();                       // (1) x ready

    // prefetch b2 slice (hidden under G2)
    float4 b2v[4];
    #pragma unroll
    for (int mf = 0; mf < 4; ++mf)
      b2v[mf] = *(const float4*)(b2 + mfw * 64 + mf * 16 + g * 4);

    // ---- G2: o = relu(x @ W2 + b2)
    #pragma unroll
    for (int i = 0; i < 8; ++i) acc[i] = (f32x4)(0.f);
    gemmWX(acc, W2s, X, mfw, nlw, lane);
    __syncthreads();                       // (2) done reading x
    uint2 opk[8];
    #pragma unroll
    for (int mf = 0; mf < 4; ++mf) {
      int f0 = mfw * 64 + mf * 16 + g * 4;
      float4 bb = b2v[mf];
      f32x4 v0 = acc[mf * 2], v1 = acc[mf * 2 + 1];
      uint2 p0 = pack4(fmaxf(v0[0] + bb.x, 0.f), fmaxf(v0[1] + bb.y, 0.f),
                       fmaxf(v0[2] + bb.z, 0.f), fmaxf(v0[3] + bb.w, 0.f));
      uint2 p1 = pack4(fmaxf(v1[0] + bb.x, 0.f), fmaxf(v1[1] + bb.y, 0.f),
                       fmaxf(v1[2] + bb.z, 0.f), fmaxf(v1[3] + bb.w, 0.f));
      opk[mf * 2] = p0; opk[mf * 2 + 1] = p1;
      int o0 = ((l0 << 8) + (f0 << 1)) ^ ((l0 & 7) << 4);
      int o1 = ((l1 << 8) + (f0 << 1)) ^ ((l1 & 7) << 4);
      *(uint2*)(X + o0) = p0;
      *(uint2*)(X + o1) = p1;
    }
    __syncthreads();                       // (3) o ready

    // prefetch gb slice (hidden under G3)
    float4 gg[4];
    #pragma unroll
    for (int mf = 0; mf < 4; ++mf)
      gg[mf] = *(const float4*)(gbv + (size_t)r * DD + mfw * 64 + mf * 16 + g * 4);

    // ---- G3: a1 = relu(o @ a1W[:128] + gb)
    #pragma unroll
    for (int i = 0; i < 8; ++i) acc[i] = (f32x4)(0.f);
    gemmWX(acc, A1s, X, mfw, nlw, lane);
    __syncthreads();                       // (4) done reading o
    #pragma unroll
    for (int mf = 0; mf < 4; ++mf) {
      int f0 = mfw * 64 + mf * 16 + g * 4;
      float4 gv = gg[mf];
      f32x4 v0 = acc[mf * 2], v1 = acc[mf * 2 + 1];
      uint2 p0 = pack4(fmaxf(v0[0] + gv.x, 0.f), fmaxf(v0[1] + gv.y, 0.f),
                       fmaxf(v0[2] + gv.z, 0.f), fmaxf(v0[3] + gv.w, 0.f));
      uint2 p1 = pack4(fmaxf(v1[0] + gv.x, 0.f), fmaxf(v1[1] + gv.y, 0.f),
                       fmaxf(v1[2] + gv.z, 0.f), fmaxf(v1[3] + gv.w, 0.f));
      int o0 = ((l0 << 8) + (f0 << 1)) ^ ((l0 & 7) << 4);
      int o1 = ((l1 << 8) + (f0 << 1)) ^ ((l1 & 7) << 4);
      *(uint2*)(X + o0) = p0;
      *(uint2*)(X + o1) = p1;
    }
    __syncthreads();                       // (5) a1 ready

    // ---- G4: a2-pre = a1 @ a2W  (A from registers)
    #pragma unroll
    for (int i = 0; i < 8; ++i) acc[i] = (f32x4)(0.f);
    #pragma unroll
    for (int kk = 0; kk < 4; ++kk) {
      bf16x8 bf0 = ldfrag(X, nlw * 32, kk, lane);
      bf16x8 bf1 = ldfrag(X, nlw * 32 + 16, kk, lane);
      #pragma unroll
      for (int mf = 0; mf < 4; ++mf) {
        bf16x8 a = a2Wr[mf * 4 + kk];
        acc[mf * 2]     = MFMA(a, bf0, acc[mf * 2]);
        acc[mf * 2 + 1] = MFMA(a, bf1, acc[mf * 2 + 1]);
      }
    }
    __syncthreads();                       // (6) done reading a1; X = tail scratch

    // logits partials: relu + dot a3W, reduce over g-groups
    {
      float s0 = 0.f, s1 = 0.f;
      #pragma unroll
      for (int mf = 0; mf < 4; ++mf) {
        float4 ab = a2br[mf], aw = a3wr[mf];
        f32x4 v0 = acc[mf * 2], v1 = acc[mf * 2 + 1];
        s0 = fmaf(fmaxf(v0[0] + ab.x, 0.f), aw.x, s0);
        s0 = fmaf(fmaxf(v0[1] + ab.y, 0.f), aw.y, s0);
        s0 = fmaf(fmaxf(v0[2] + ab.z, 0.f), aw.z, s0);
        s0 = fmaf(fmaxf(v0[3] + ab.w, 0.f), aw.w, s0);
        s1 = fmaf(fmaxf(v1[0] + ab.x, 0.f), aw.x, s1);
        s1 = fmaf(fmaxf(v1[1] + ab.y, 0.f), aw.y, s1);
        s1 = fmaf(fmaxf(v1[2] + ab.z, 0.f), aw.z, s1);
        s1 = fmaf(fmaxf(v1[3] + ab.w, 0.f), aw.w, s1);
      }
      s0 += __shfl_xor(s0, 16); s0 += __shfl_xor(s0, 32);
      s1 += __shfl_xor(s1, 16); s1 += __shfl_xor(s1, 32);
      if (g == 0) {                        // lpart[mfw][l] at X + mfw*256 + l*4
        *(float*)(X + mfw * 256 + l0 * 4) = s0;
        *(float*)(X + mfw * 256 + l1 * 4) = s1;
      }
    }
    __syncthreads();                       // (7) lpart ready

    // masked softmax (wave 0 -> row A, wave 4 -> row B)
    if (w4 == 0) {
      int l = lane;
      float lv = *(const float*)(X + l * 4) + *(const float*)(X + 256 + l * 4) + a3bv;
      int len = hlen[r] + 1;
      bool valid = l < len;
      if (!valid) lv = -1e30f;
      float m = lv;
      #pragma unroll
      for (int off = 32; off; off >>= 1) m = fmaxf(m, __shfl_xor(m, off));
      float pe = valid ? expf(lv - m) : 0.f;
      float s = pe;
      #pragma unroll
      for (int off = 32; off; off >>= 1) s += __shfl_xor(s, off);
      *(float*)(X + 512 + l * 4) = pe / s;
    }
    __syncthreads();                       // (8) att ready

    // out-reduce from register o copy
    {
      float att0 = *(const float*)(X + 512 + l0 * 4);
      float att1 = *(const float*)(X + 512 + l1 * 4);
      float pr[4][4];
      #pragma unroll
      for (int mf = 0; mf < 4; ++mf) {
        uint2 q0 = opk[mf * 2], q1 = opk[mf * 2 + 1];
        pr[mf][0] = att0 * __uint_as_float(q0.x << 16)
                  + att1 * __uint_as_float(q1.x << 16);
        pr[mf][1] = att0 * __uint_as_float(q0.x & 0xffff0000u)
                  + att1 * __uint_as_float(q1.x & 0xffff0000u);
        pr[mf][2] = att0 * __uint_as_float(q0.y << 16)
                  + att1 * __uint_as_float(q1.y << 16);
        pr[mf][3] = att0 * __uint_as_float(q0.y & 0xffff0000u)
                  + att1 * __uint_as_float(q1.y & 0xffff0000u);
      }
      #pragma unroll
      for (int m = 1; m < 16; m <<= 1) {
        #pragma unroll
        for (int mf = 0; mf < 4; ++mf) {
          pr[mf][0] += __shfl_xor(pr[mf][0], m);
          pr[mf][1] += __shfl_xor(pr[mf][1], m);
          pr[mf][2] += __shfl_xor(pr[mf][2], m);
          pr[mf][3] += __shfl_xor(pr[mf][3], m);
        }
      }
      if (cb == 0) {                       // red[nlw][f] at X + 1024 + nlw*512 + f*4
        #pragma unroll
        for (int mf = 0; mf < 4; ++mf) {
          int f0 = mfw * 64 + mf * 16 + g * 4;
          float* rd = (float*)(X + 1024 + nlw * 512);
          rd[f0 + 0] = pr[mf][0];
          rd[f0 + 1] = pr[mf][1];
          rd[f0 + 2] = pr[mf][2];
          rd[f0 + 3] = pr[mf][3];
        }
      }
    }
    __syncthreads();                       // (9) red ready

    if (tid < 128 || (tid >= 256 && tid < 384)) {
      int d = tid & 127;
      out[(size_t)r * DD + d] = *(const float*)(X + 1024 + d * 4)
                              + *(const float*)(X + 1536 + d * 4);
    }
    __syncthreads();                       // (10) X free for next pair

    hu0 = hu0n; hu1 = hu1n; hr0 = hr0n; hr1 = hr1n;
    r += 2;
  }
}

extern "C" void kernel_launch(void* const* d_in, const int* in_sizes, int n_in,
                              void* d_out, int out_size, void* d_ws, size_t ws_size,
                              hipStream_t stream) {
  const int*   nodes = (const int*)d_in[0];
  const int*   hu    = (const int*)d_in[1];
  const int*   hr    = (const int*)d_in[2];
  const int*   hlen  = (const int*)d_in[3];
  const float* v2e   = (const float*)d_in[4];
  const float* u2e   = (const float*)d_in[5];
  const float* r2e   = (const float*)d_in[6];
  const float* W1    = (const float*)d_in[7];
  const float* b1    = (const float*)d_in[8];
  const float* W2    = (const float*)d_in[9];
  const float* b2    = (const float*)d_in[10];
  const float* a1W   = (const float*)d_in[11];
  const float* a1b   = (const float*)d_in[12];
  const float* a2W   = (const float*)d_in[13];
  const float* a2b   = (const float*)d_in[14];
  const float* a3W   = (const float*)d_in[15];
  const float* a3b   = (const float*)d_in[16];
  const float* geW   = (const float*)d_in[17];
  const float* geb   = (const float*)d_in[18];
  float* out = (float*)d_out;

  unsigned short* wsw = (unsigned short*)d_ws;
  const char* tiles = (const char*)d_ws;
  float* Rp  = (float*)((char*)d_ws + WS_R_OFF);
  float* gbv = (float*)((char*)d_ws + WS_GB_OFF);

  prep_weights<<<49, 256, 0, stream>>>(W1, W2, a1W, a2W, geW, r2e, b1, wsw, Rp);
  prep_gb<<<256, 256, 0, stream>>>(nodes, u2e, geb, a1b, tiles, gbv);
  main_kernel<<<256, 512, 0, stream>>>(
      hu, hr, hlen, v2e, b2, a2b, a3W, a3b, tiles, Rp, gbv, out);
}

// Round 7
// 217.905 us; speedup vs baseline: 1.6232x; 1.6232x over previous
//
#include <hip/hip_runtime.h>
#include <hip/hip_bf16.h>

#define DD 128
#define TILE_BYTES 32768
#define WS_R_OFF   196608            // 6 tiles * 32768
#define WS_GB_OFF  199168            // + 640*4 (R')

typedef __attribute__((ext_vector_type(8))) short bf16x8;
typedef __attribute__((ext_vector_type(4))) float f32x4;

__device__ inline unsigned short f2bf(float f) {
  unsigned u = __float_as_uint(f);
  return (unsigned short)((u + 0x7fffu + ((u >> 16) & 1u)) >> 16);   // RNE
}

// async global->LDS, 16B per lane; LDS dest is wave-uniform base + lane*16
__device__ inline void async16(void* ldsp, const void* gp) {
  __builtin_amdgcn_global_load_lds(
      (const __attribute__((address_space(1))) void*)gp,
      (__attribute__((address_space(3))) void*)ldsp, 16, 0, 0);
}

// fill a 32 KB LDS weight slot from a pre-swizzled global image (256 threads)
__device__ inline void fill_w(char* slot, const char* src, int tid) {
  int w = tid >> 6, lane = tid & 63;
  #pragma unroll
  for (int i = 0; i < 8; ++i) {
    int ofs = ((i << 2) + w) << 10;            // 1 KB per wave-chunk
    async16(slot + ofs, src + ofs + lane * 16);
  }
}

// read a 16x32 bf16 MFMA fragment from a swizzled [rows][128] bf16 tile
__device__ inline bf16x8 ldfrag(const char* buf, int rowbase, int kk, int lane) {
  int row = rowbase + (lane & 15);
  int off = (row << 8) + (kk << 6) + (lane & 48);
  off ^= (row & 7) << 4;
  return *(const bf16x8*)(buf + off);
}

__device__ inline uint2 pack4(float v0, float v1, float v2, float v3) {
  return make_uint2((unsigned)f2bf(v0) | ((unsigned)f2bf(v1) << 16),
                    (unsigned)f2bf(v2) | ((unsigned)f2bf(v3) << 16));
}

// convert two prefetched float4 pairs into a bf16x8 fragment
__device__ inline bf16x8 cvt8(float4 f0, float4 f1) {
  bf16x8 r;
  r[0] = (short)f2bf(f0.x); r[1] = (short)f2bf(f0.y);
  r[2] = (short)f2bf(f0.z); r[3] = (short)f2bf(f0.w);
  r[4] = (short)f2bf(f1.x); r[5] = (short)f2bf(f1.y);
  r[6] = (short)f2bf(f1.z); r[7] = (short)f2bf(f1.w);
  return r;
}

#define MFMA(a, b, c) __builtin_amdgcn_mfma_f32_16x16x32_bf16((a), (b), (c), 0, 0, 0)

// ---------------- pre-kernel 1: weight tiles (bf16, [n][k], pre-swizzled) + R' ----------------
__global__ __launch_bounds__(256) void prep_weights(
    const float* __restrict__ W1, const float* __restrict__ W2,
    const float* __restrict__ a1W, const float* __restrict__ a2W,
    const float* __restrict__ geW,
    const float* __restrict__ r2e, const float* __restrict__ b1,
    unsigned short* __restrict__ wsw, float* __restrict__ Rp) {
  int gid = blockIdx.x * 256 + threadIdx.x;
  if (gid < 12288) {
    int tile = gid >> 11, idx = gid & 2047;
    int row = idx >> 4, slot = idx & 15;
    int slot2 = slot ^ (row & 7);              // inverse swizzle on source
    const float* W; int kb;
    switch (tile) {
      case 0:  W = W1;  kb = 0;   break;       // W1[:128]
      case 1:  W = W2;  kb = 0;   break;
      case 2:  W = a1W; kb = 0;   break;       // a1W[:128]
      case 3:  W = a2W; kb = 0;   break;
      case 4:  W = geW; kb = 0;   break;
      default: W = a1W; kb = 128; break;       // a1W[128:]
    }
    unsigned pk[4];
    #pragma unroll
    for (int p = 0; p < 4; ++p) {
      unsigned short lo = f2bf(W[(size_t)(kb + slot2 * 8 + 2 * p) * DD + row]);
      unsigned short hi = f2bf(W[(size_t)(kb + slot2 * 8 + 2 * p + 1) * DD + row]);
      pk[p] = (unsigned)lo | ((unsigned)hi << 16);
    }
    *(uint4*)(wsw + (size_t)tile * 16384 + (size_t)idx * 8) =
        make_uint4(pk[0], pk[1], pk[2], pk[3]);
  } else {
    // R'[5][128] = r2e @ W1[128:] + b1   (fp32 exact)
    int t = gid - 12288;
    for (int idx = t; idx < 640; idx += 256) {
      int r = idx >> 7, d = idx & 127;
      float s = b1[d];
      for (int k = 0; k < 128; ++k)
        s = fmaf(r2e[r * DD + k], W1[(size_t)(DD + k) * DD + d], s);
      Rp[idx] = s;
    }
  }
}

// ---------------- pre-kernel 2: gb[b][d] = a1b + relu(mean@geW+geb)@a1W[D:] ----------------
__global__ __launch_bounds__(256, 2) void prep_gb(
    const int* __restrict__ nodes, const float* __restrict__ u2e,
    const float* __restrict__ geb, const float* __restrict__ a1b,
    const char* __restrict__ tiles, float* __restrict__ gbv) {
  __shared__ char mean_s[4096];    // [16][128] bf16 swizzled
  __shared__ char g_s[4096];
  __shared__ char wslot[32768];
  __shared__ int nodes_s[128];
  int tid = threadIdx.x, w = tid >> 6, lane = tid & 63;
  int b0 = blockIdx.x * 16;
  if (tid < 128) nodes_s[tid] = nodes[b0 * 8 + tid];
  fill_w(wslot, tiles + 4 * TILE_BYTES, tid);      // geW
  __syncthreads();
  for (int idx = tid; idx < 2048; idx += 256) {
    int row = idx >> 7, d = idx & 127;
    float m = 0.f;
    #pragma unroll
    for (int j = 0; j < 8; ++j)
      m += u2e[(size_t)nodes_s[row * 8 + j] * DD + d];
    m *= 0.125f;
    int off = ((row << 8) + (d << 1)) ^ ((row & 7) << 4);
    *(unsigned short*)(mean_s + off) = f2bf(m);
  }
  __syncthreads();
  int cb = lane & 15, rb = (lane >> 4) << 2;
  f32x4 acc[2] = {(f32x4)(0.f), (f32x4)(0.f)};
  #pragma unroll
  for (int kk = 0; kk < 4; ++kk) {
    bf16x8 a = ldfrag(mean_s, 0, kk, lane);
    #pragma unroll
    for (int nf = 0; nf < 2; ++nf) {
      bf16x8 b = ldfrag(wslot, w * 32 + nf * 16, kk, lane);
      acc[nf] = MFMA(a, b, acc[nf]);
    }
  }
  __syncthreads();
  fill_w(wslot, tiles + 5 * TILE_BYTES, tid);      // a1W[128:]
  #pragma unroll
  for (int nf = 0; nf < 2; ++nf) {
    int col = w * 32 + nf * 16 + cb;
    float gb2 = geb[col];
    #pragma unroll
    for (int j = 0; j < 4; ++j) {
      int row = rb + j;
      float v = fmaxf(acc[nf][j] + gb2, 0.f);
      int off = ((row << 8) + (col << 1)) ^ ((row & 7) << 4);
      *(unsigned short*)(g_s + off) = f2bf(v);
    }
  }
  __syncthreads();
  acc[0] = (f32x4)(0.f); acc[1] = (f32x4)(0.f);
  #pragma unroll
  for (int kk = 0; kk < 4; ++kk) {
    bf16x8 a = ldfrag(g_s, 0, kk, lane);
    #pragma unroll
    for (int nf = 0; nf < 2; ++nf) {
      bf16x8 b = ldfrag(wslot, w * 32 + nf * 16, kk, lane);
      acc[nf] = MFMA(a, b, acc[nf]);
    }
  }
  #pragma unroll
  for (int nf = 0; nf < 2; ++nf) {
    int col = w * 32 + nf * 16 + cb;
    float bb = a1b[col];
    #pragma unroll
    for (int j = 0; j < 4; ++j)
      gbv[(size_t)(b0 + rb + j) * DD + col] = acc[nf][j] + bb;
  }
}

// 64f x 32l wave-tile GEMM over K=128 (A,B swizzled LDS tiles)
__device__ inline void gemmWX(f32x4 acc[8], const char* Wt, const char* Xt,
                              int mfw, int nlw, int lane) {
  #pragma unroll
  for (int kk = 0; kk < 4; ++kk) {
    bf16x8 bf0 = ldfrag(Xt, nlw * 32, kk, lane);
    bf16x8 bf1 = ldfrag(Xt, nlw * 32 + 16, kk, lane);
    #pragma unroll
    for (int mf = 0; mf < 4; ++mf) {
      bf16x8 a = ldfrag(Wt, mfw * 64 + mf * 16, kk, lane);
      acc[mf * 2]     = MFMA(a, bf0, acc[mf * 2]);
      acc[mf * 2 + 1] = MFMA(a, bf1, acc[mf * 2 + 1]);
    }
  }
}

// ---------------- main: weights-resident, 16 rows/block as 8 pairs ----------------
__global__ __launch_bounds__(512, 1) void main_kernel(
    const int* __restrict__ hu, const int* __restrict__ hr,
    const int* __restrict__ hlen,
    const float* __restrict__ v2e,
    const float* __restrict__ b2, const float* __restrict__ a2b,
    const float* __restrict__ a3W, const float* __restrict__ a3b,
    const char* __restrict__ tiles, const float* __restrict__ Rp,
    const float* __restrict__ gbv, float* __restrict__ out) {
  __shared__ char smem[133760];
  char*  W1s = smem;                 // 32768  (resident all kernel)
  char*  W2s = smem + 32768;         // 32768
  char*  A1s = smem + 65536;         // 32768
  char*  XA  = smem + 98304;         // 16384 (row A: x -> o -> a1 -> tail scratch)
  char*  XB  = smem + 114688;        // 16384 (row B)
  float* Rs  = (float*)(smem + 131072);  // [5][132] padded, 2640 B

  const int tid = threadIdx.x, lane = tid & 63;
  const int wv = tid >> 6;
  const int rowsel = wv >> 2;              // 0: row A, 1: row B
  const int w4 = wv & 3;
  const int mfw = w4 >> 1, nlw = w4 & 1;   // 64f x 32l wave tile
  const int cb = lane & 15, g = lane >> 4;
  char* X = rowsel ? XB : XA;

  // ---- prologue: resident weight fills (once per block) ----
  #pragma unroll
  for (int i = 0; i < 4; ++i) {
    int ofs = (i * 8 + wv) << 10;          // 8 waves x 4 sweeps x 1 KB
    async16(W1s + ofs, tiles + ofs + lane * 16);
    async16(W2s + ofs, tiles + TILE_BYTES + ofs + lane * 16);
    async16(A1s + ofs, tiles + 2 * TILE_BYTES + ofs + lane * 16);
  }
  for (int i = tid; i < 640; i += 512)
    Rs[(i >> 7) * 132 + (i & 127)] = Rp[i];

  // a2W fragments resident in registers (16 x bf16x8 = 64 VGPR)
  bf16x8 a2Wr[16];
  {
    const char* a2g = tiles + 3 * TILE_BYTES;
    #pragma unroll
    for (int mf = 0; mf < 4; ++mf)
      #pragma unroll
      for (int kk = 0; kk < 4; ++kk) {
        int row = mfw * 64 + mf * 16 + cb;
        int off = ((row << 8) + (kk << 6) + (lane & 48)) ^ ((row & 7) << 4);
        a2Wr[mf * 4 + kk] = *(const bf16x8*)(a2g + off);
      }
  }
  const float a3bv = a3b[0];

  const int l0 = nlw * 32 + cb, l1 = l0 + 16;
  const int rbase = blockIdx.x * 16;
  int r = rbase + rowsel;
  int hu0 = hu[r * 64 + l0], hu1 = hu[r * 64 + l1];
  int hr0 = hr[r * 64 + l0], hr1 = hr[r * 64 + l1];

  // v2e prefetch for pair 0 (fp32, converted at use)
  float4 vpre[16];
  {
    const float* rp0 = v2e + (size_t)hu0 * DD;
    const float* rp1 = v2e + (size_t)hu1 * DD;
    #pragma unroll
    for (int kk = 0; kk < 4; ++kk) {
      const float4* q0 = (const float4*)(rp0 + (kk << 5) + (g << 3));
      const float4* q1 = (const float4*)(rp1 + (kk << 5) + (g << 3));
      vpre[kk * 4 + 0] = q0[0]; vpre[kk * 4 + 1] = q0[1];
      vpre[kk * 4 + 2] = q1[0]; vpre[kk * 4 + 3] = q1[1];
    }
  }
  __syncthreads();                         // weights + R' resident

  for (int p = 0; p < 8; ++p) {
    // next pair's history indices (issued early; used for v2e prefetch below)
    int hu0n = 0, hu1n = 0, hr0n = 0, hr1n = 0;
    if (p < 7) {
      int rn = r + 2;
      hu0n = hu[rn * 64 + l0]; hu1n = hu[rn * 64 + l1];
      hr0n = hr[rn * 64 + l0]; hr1n = hr[rn * 64 + l1];
    }

    f32x4 acc[8];
    #pragma unroll
    for (int i = 0; i < 8; ++i) acc[i] = (f32x4)(0.f);

    // ---- G1: x = e_uv @ W1[:128]; B from prefetched registers
    #pragma unroll
    for (int kk = 0; kk < 4; ++kk) {
      bf16x8 bf0 = cvt8(vpre[kk * 4 + 0], vpre[kk * 4 + 1]);
      bf16x8 bf1 = cvt8(vpre[kk * 4 + 2], vpre[kk * 4 + 3]);
      #pragma unroll
      for (int mf = 0; mf < 4; ++mf) {
        bf16x8 a = ldfrag(W1s, mfw * 64 + mf * 16, kk, lane);
        acc[mf * 2]     = MFMA(a, bf0, acc[mf * 2]);
        acc[mf * 2 + 1] = MFMA(a, bf1, acc[mf * 2 + 1]);
      }
    }
    // issue next pair's v2e prefetch (hides under G2..G4)
    if (p < 7) {
      const float* rp0 = v2e + (size_t)hu0n * DD;
      const float* rp1 = v2e + (size_t)hu1n * DD;
      #pragma unroll
      for (int kk = 0; kk < 4; ++kk) {
        const float4* q0 = (const float4*)(rp0 + (kk << 5) + (g << 3));
        const float4* q1 = (const float4*)(rp1 + (kk << 5) + (g << 3));
        vpre[kk * 4 + 0] = q0[0]; vpre[kk * 4 + 1] = q0[1];
        vpre[kk * 4 + 2] = q1[0]; vpre[kk * 4 + 3] = q1[1];
      }
    }
    // epi1: +R'[hr], relu -> X
    #pragma unroll
    for (int mf = 0; mf < 4; ++mf) {
      int f0 = mfw * 64 + mf * 16 + g * 4;
      float4 r0 = *(const float4*)(Rs + hr0 * 132 + f0);
      float4 r1 = *(const float4*)(Rs + hr1 * 132 + f0);
      f32x4 v0 = acc[mf * 2], v1 = acc[mf * 2 + 1];
      uint2 p0 = pack4(fmaxf(v0[0] + r0.x, 0.f), fmaxf(v0[1] + r0.y, 0.f),
                       fmaxf(v0[2] + r0.z, 0.f), fmaxf(v0[3] + r0.w, 0.f));
      uint2 p1 = pack4(fmaxf(v1[0] + r1.x, 0.f), fmaxf(v1[1] + r1.y, 0.f),
                       fmaxf(v1[2] + r1.z, 0.f), fmaxf(v1[3] + r1.w, 0.f));
      int o0 = ((l0 << 8) + (f0 << 1)) ^ ((l0 & 7) << 4);
      int o1 = ((l1 << 8) + (f0 << 1)) ^ ((l1 & 7) << 4);
      *(uint2*)(X + o0) = p0;
      *(uint2*)(X + o1) = p1;
    }
    __syncthreads();                       // (1) x ready

    // prefetch b2 slice (hidden under G2)
    float4 b2v[4];
    #pragma unroll
    for (int mf = 0; mf < 4; ++mf)
      b2v[mf] = *(const float4*)(b2 + mfw * 64 + mf * 16 + g * 4);

    // ---- G2: o = relu(x @ W2 + b2)
    #pragma unroll
    for (int i = 0; i < 8; ++i) acc[i] = (f32x4)(0.f);
    gemmWX(acc, W2s, X, mfw, nlw, lane);
    __syncthreads();                       // (2) done reading x
    uint2 opk[8];
    #pragma unroll
    for (int mf = 0; mf < 4; ++mf) {
      int f0 = mfw * 64 + mf * 16 + g * 4;
      float4 bb = b2v[mf];
      f32x4 v0 = acc[mf * 2], v1 = acc[mf * 2 + 1];
      uint2 p0 = pack4(fmaxf(v0[0] + bb.x, 0.f), fmaxf(v0[1] + bb.y, 0.f),
                       fmaxf(v0[2] + bb.z, 0.f), fmaxf(v0[3] + bb.w, 0.f));
      uint2 p1 = pack4(fmaxf(v1[0] + bb.x, 0.f), fmaxf(v1[1] + bb.y, 0.f),
                       fmaxf(v1[2] + bb.z, 0.f), fmaxf(v1[3] + bb.w, 0.f));
      opk[mf * 2] = p0; opk[mf * 2 + 1] = p1;
      int o0 = ((l0 << 8) + (f0 << 1)) ^ ((l0 & 7) << 4);
      int o1 = ((l1 << 8) + (f0 << 1)) ^ ((l1 & 7) << 4);
      *(uint2*)(X + o0) = p0;
      *(uint2*)(X + o1) = p1;
    }
    __syncthreads();                       // (3) o ready

    // prefetch gb slice (hidden under G3)
    float4 gg[4];
    #pragma unroll
    for (int mf = 0; mf < 4; ++mf)
      gg[mf] = *(const float4*)(gbv + (size_t)r * DD + mfw * 64 + mf * 16 + g * 4);

    // ---- G3: a1 = relu(o @ a1W[:128] + gb)
    #pragma unroll
    for (int i = 0; i < 8; ++i) acc[i] = (f32x4)(0.f);
    gemmWX(acc, A1s, X, mfw, nlw, lane);
    __syncthreads();                       // (4) done reading o
    #pragma unroll
    for (int mf = 0; mf < 4; ++mf) {
      int f0 = mfw * 64 + mf * 16 + g * 4;
      float4 gv = gg[mf];
      f32x4 v0 = acc[mf * 2], v1 = acc[mf * 2 + 1];
      uint2 p0 = pack4(fmaxf(v0[0] + gv.x, 0.f), fmaxf(v0[1] + gv.y, 0.f),
                       fmaxf(v0[2] + gv.z, 0.f), fmaxf(v0[3] + gv.w, 0.f));
      uint2 p1 = pack4(fmaxf(v1[0] + gv.x, 0.f), fmaxf(v1[1] + gv.y, 0.f),
                       fmaxf(v1[2] + gv.z, 0.f), fmaxf(v1[3] + gv.w, 0.f));
      int o0 = ((l0 << 8) + (f0 << 1)) ^ ((l0 & 7) << 4);
      int o1 = ((l1 << 8) + (f0 << 1)) ^ ((l1 & 7) << 4);
      *(uint2*)(X + o0) = p0;
      *(uint2*)(X + o1) = p1;
    }
    __syncthreads();                       // (5) a1 ready

    // ---- G4: a2-pre = a1 @ a2W  (A from registers)
    #pragma unroll
    for (int i = 0; i < 8; ++i) acc[i] = (f32x4)(0.f);
    #pragma unroll
    for (int kk = 0; kk < 4; ++kk) {
      bf16x8 bf0 = ldfrag(X, nlw * 32, kk, lane);
      bf16x8 bf1 = ldfrag(X, nlw * 32 + 16, kk, lane);
      #pragma unroll
      for (int mf = 0; mf < 4; ++mf) {
        bf16x8 a = a2Wr[mf * 4 + kk];
        acc[mf * 2]     = MFMA(a, bf0, acc[mf * 2]);
        acc[mf * 2 + 1] = MFMA(a, bf1, acc[mf * 2 + 1]);
      }
    }
    __syncthreads();                       // (6) done reading a1; X = tail scratch

    // logits partials: relu + dot a3W, reduce over g-groups
    {
      float s0 = 0.f, s1 = 0.f;
      #pragma unroll
      for (int mf = 0; mf < 4; ++mf) {
        int f0 = mfw * 64 + mf * 16 + g * 4;
        float4 ab = *(const float4*)(a2b + f0);
        float4 aw = *(const float4*)(a3W + f0);
        f32x4 v0 = acc[mf * 2], v1 = acc[mf * 2 + 1];
        s0 = fmaf(fmaxf(v0[0] + ab.x, 0.f), aw.x, s0);
        s0 = fmaf(fmaxf(v0[1] + ab.y, 0.f), aw.y, s0);
        s0 = fmaf(fmaxf(v0[2] + ab.z, 0.f), aw.z, s0);
        s0 = fmaf(fmaxf(v0[3] + ab.w, 0.f), aw.w, s0);
        s1 = fmaf(fmaxf(v1[0] + ab.x, 0.f), aw.x, s1);
        s1 = fmaf(fmaxf(v1[1] + ab.y, 0.f), aw.y, s1);
        s1 = fmaf(fmaxf(v1[2] + ab.z, 0.f), aw.z, s1);
        s1 = fmaf(fmaxf(v1[3] + ab.w, 0.f), aw.w, s1);
      }
      s0 += __shfl_xor(s0, 16); s0 += __shfl_xor(s0, 32);
      s1 += __shfl_xor(s1, 16); s1 += __shfl_xor(s1, 32);
      if (g == 0) {                        // lpart[mfw][l] at X + mfw*256 + l*4
        *(float*)(X + mfw * 256 + l0 * 4) = s0;
        *(float*)(X + mfw * 256 + l1 * 4) = s1;
      }
    }
    __syncthreads();                       // (7) lpart ready

    // masked softmax (wave 0 -> row A, wave 4 -> row B)
    if (w4 == 0) {
      int l = lane;
      float lv = *(const float*)(X + l * 4) + *(const float*)(X + 256 + l * 4) + a3bv;
      int len = hlen[r] + 1;
      bool valid = l < len;
      if (!valid) lv = -1e30f;
      float m = lv;
      #pragma unroll
      for (int off = 32; off; off >>= 1) m = fmaxf(m, __shfl_xor(m, off));
      float pe = valid ? expf(lv - m) : 0.f;
      float s = pe;
      #pragma unroll
      for (int off = 32; off; off >>= 1) s += __shfl_xor(s, off);
      *(float*)(X + 512 + l * 4) = pe / s;
    }
    __syncthreads();                       // (8) att ready

    // out-reduce from register o copy
    {
      float att0 = *(const float*)(X + 512 + l0 * 4);
      float att1 = *(const float*)(X + 512 + l1 * 4);
      float pr[4][4];
      #pragma unroll
      for (int mf = 0; mf < 4; ++mf) {
        uint2 q0 = opk[mf * 2], q1 = opk[mf * 2 + 1];
        pr[mf][0] = att0 * __uint_as_float(q0.x << 16)
                  + att1 * __uint_as_float(q1.x << 16);
        pr[mf][1] = att0 * __uint_as_float(q0.x & 0xffff0000u)
                  + att1 * __uint_as_float(q1.x & 0xffff0000u);
        pr[mf][2] = att0 * __uint_as_float(q0.y << 16)
                  + att1 * __uint_as_float(q1.y << 16);
        pr[mf][3] = att0 * __uint_as_float(q0.y & 0xffff0000u)
                  + att1 * __uint_as_float(q1.y & 0xffff0000u);
      }
      #pragma unroll
      for (int m = 1; m < 16; m <<= 1) {
        #pragma unroll
        for (int mf = 0; mf < 4; ++mf) {
          pr[mf][0] += __shfl_xor(pr[mf][0], m);
          pr[mf][1] += __shfl_xor(pr[mf][1], m);
          pr[mf][2] += __shfl_xor(pr[mf][2], m);
          pr[mf][3] += __shfl_xor(pr[mf][3], m);
        }
      }
      if (cb == 0) {                       // red[nlw][f] at X + 1024 + nlw*512 + f*4
        #pragma unroll
        for (int mf = 0; mf < 4; ++mf) {
          int f0 = mfw * 64 + mf * 16 + g * 4;
          float* rd = (float*)(X + 1024 + nlw * 512);
          rd[f0 + 0] = pr[mf][0];
          rd[f0 + 1] = pr[mf][1];
          rd[f0 + 2] = pr[mf][2];
          rd[f0 + 3] = pr[mf][3];
        }
      }
    }
    __syncthreads();                       // (9) red ready

    if (tid < 128 || (tid >= 256 && tid < 384)) {
      int d = tid & 127;
      out[(size_t)r * DD + d] = *(const float*)(X + 1024 + d * 4)
                              + *(const float*)(X + 1536 + d * 4);
    }
    __syncthreads();                       // (10) X free for next pair

    hu0 = hu0n; hu1 = hu1n; hr0 = hr0n; hr1 = hr1n;
    r += 2;
  }
}

extern "C" void kernel_launch(void* const* d_in, const int* in_sizes, int n_in,
                              void* d_out, int out_size, void* d_ws, size_t ws_size,
                              hipStream_t stream) {
  const int*   nodes = (const int*)d_in[0];
  const int*   hu    = (const int*)d_in[1];
  const int*   hr    = (const int*)d_in[2];
  const int*   hlen  = (const int*)d_in[3];
  const float* v2e   = (const float*)d_in[4];
  const float* u2e   = (const float*)d_in[5];
  const float* r2e   = (const float*)d_in[6];
  const float* W1    = (const float*)d_in[7];
  const float* b1    = (const float*)d_in[8];
  const float* W2    = (const float*)d_in[9];
  const float* b2    = (const float*)d_in[10];
  const float* a1W   = (const float*)d_in[11];
  const float* a1b   = (const float*)d_in[12];
  const float* a2W   = (const float*)d_in[13];
  const float* a2b   = (const float*)d_in[14];
  const float* a3W   = (const float*)d_in[15];
  const float* a3b   = (const float*)d_in[16];
  const float* geW   = (const float*)d_in[17];
  const float* geb   = (const float*)d_in[18];
  float* out = (float*)d_out;

  unsigned short* wsw = (unsigned short*)d_ws;
  const char* tiles = (const char*)d_ws;
  float* Rp  = (float*)((char*)d_ws + WS_R_OFF);
  float* gbv = (float*)((char*)d_ws + WS_GB_OFF);

  prep_weights<<<49, 256, 0, stream>>>(W1, W2, a1W, a2W, geW, r2e, b1, wsw, Rp);
  prep_gb<<<256, 256, 0, stream>>>(nodes, u2e, geb, a1b, tiles, gbv);
  main_kernel<<<256, 512, 0, stream>>>(
      hu, hr, hlen, v2e, b2, a2b, a3W, a3b, tiles, Rp, gbv, out);
}

// Round 8
// 121.328 us; speedup vs baseline: 2.9154x; 1.7960x over previous
//
#include <hip/hip_runtime.h>
#include <hip/hip_bf16.h>

#define DD 128
#define TILE_BYTES 32768
#define WS_R_OFF   196608            // 6 tiles * 32768
#define WS_GB_OFF  199168            // + 640*4 (R')

typedef __attribute__((ext_vector_type(8))) short bf16x8;
typedef __attribute__((ext_vector_type(4))) float f32x4;

__device__ inline unsigned short f2bf(float f) {
  unsigned u = __float_as_uint(f);
  return (unsigned short)((u + 0x7fffu + ((u >> 16) & 1u)) >> 16);   // RNE
}

// async global->LDS, 16B per lane; LDS dest is wave-uniform base + lane*16
__device__ inline void async16(void* ldsp, const void* gp) {
  __builtin_amdgcn_global_load_lds(
      (const __attribute__((address_space(1))) void*)gp,
      (__attribute__((address_space(3))) void*)ldsp, 16, 0, 0);
}

// fill a 32 KB LDS weight slot from a pre-swizzled global image (256 threads)
__device__ inline void fill_w(char* slot, const char* src, int tid) {
  int w = tid >> 6, lane = tid & 63;
  #pragma unroll
  for (int i = 0; i < 8; ++i) {
    int ofs = ((i << 2) + w) << 10;            // 1 KB per wave-chunk
    async16(slot + ofs, src + ofs + lane * 16);
  }
}

// read a 16x32 bf16 MFMA fragment from a swizzled [rows][128] bf16 tile
__device__ inline bf16x8 ldfrag(const char* buf, int rowbase, int kk, int lane) {
  int row = rowbase + (lane & 15);
  int off = (row << 8) + (kk << 6) + (lane & 48);
  off ^= (row & 7) << 4;
  return *(const bf16x8*)(buf + off);
}

// build a fragment directly from a global fp32 row (8 floats -> bf16x8)
__device__ inline bf16x8 ldAg(const float* rp, int kk, int lane) {
  const float4* p = (const float4*)(rp + (kk << 5) + ((lane >> 4) << 3));
  float4 f0 = p[0], f1 = p[1];
  bf16x8 r;
  r[0] = (short)f2bf(f0.x); r[1] = (short)f2bf(f0.y);
  r[2] = (short)f2bf(f0.z); r[3] = (short)f2bf(f0.w);
  r[4] = (short)f2bf(f1.x); r[5] = (short)f2bf(f1.y);
  r[6] = (short)f2bf(f1.z); r[7] = (short)f2bf(f1.w);
  return r;
}

__device__ inline uint2 pack4(float v0, float v1, float v2, float v3) {
  return make_uint2((unsigned)f2bf(v0) | ((unsigned)f2bf(v1) << 16),
                    (unsigned)f2bf(v2) | ((unsigned)f2bf(v3) << 16));
}

#define MFMA(a, b, c) __builtin_amdgcn_mfma_f32_16x16x32_bf16((a), (b), (c), 0, 0, 0)

// ---------------- pre-kernel 1: weight tiles (bf16, [n][k], pre-swizzled) + R' ----------------
__global__ __launch_bounds__(256) void prep_weights(
    const float* __restrict__ W1, const float* __restrict__ W2,
    const float* __restrict__ a1W, const float* __restrict__ a2W,
    const float* __restrict__ geW,
    const float* __restrict__ r2e, const float* __restrict__ b1,
    unsigned short* __restrict__ wsw, float* __restrict__ Rp) {
  int gid = blockIdx.x * 256 + threadIdx.x;
  if (gid < 12288) {
    int tile = gid >> 11, idx = gid & 2047;
    int row = idx >> 4, slot = idx & 15;
    int slot2 = slot ^ (row & 7);              // inverse swizzle on source
    const float* W; int kb;
    switch (tile) {
      case 0:  W = W1;  kb = 0;   break;       // W1[:128]
      case 1:  W = W2;  kb = 0;   break;
      case 2:  W = a1W; kb = 0;   break;       // a1W[:128]
      case 3:  W = a2W; kb = 0;   break;
      case 4:  W = geW; kb = 0;   break;
      default: W = a1W; kb = 128; break;       // a1W[128:]
    }
    unsigned pk[4];
    #pragma unroll
    for (int p = 0; p < 4; ++p) {
      unsigned short lo = f2bf(W[(size_t)(kb + slot2 * 8 + 2 * p) * DD + row]);
      unsigned short hi = f2bf(W[(size_t)(kb + slot2 * 8 + 2 * p + 1) * DD + row]);
      pk[p] = (unsigned)lo | ((unsigned)hi << 16);
    }
    *(uint4*)(wsw + (size_t)tile * 16384 + (size_t)idx * 8) =
        make_uint4(pk[0], pk[1], pk[2], pk[3]);
  } else {
    // R'[5][128] = r2e @ W1[128:] + b1   (fp32 exact)
    int t = gid - 12288;
    for (int idx = t; idx < 640; idx += 256) {
      int r = idx >> 7, d = idx & 127;
      float s = b1[d];
      for (int k = 0; k < 128; ++k)
        s = fmaf(r2e[r * DD + k], W1[(size_t)(DD + k) * DD + d], s);
      Rp[idx] = s;
    }
  }
}

// ---------------- pre-kernel 2: gb[b][d] = a1b + relu(mean@geW+geb)@a1W[D:] ----------------
__global__ __launch_bounds__(256, 2) void prep_gb(
    const int* __restrict__ nodes, const float* __restrict__ u2e,
    const float* __restrict__ geb, const float* __restrict__ a1b,
    const char* __restrict__ tiles, float* __restrict__ gbv) {
  __shared__ char mean_s[4096];    // [16][128] bf16 swizzled
  __shared__ char g_s[4096];
  __shared__ char wslot[32768];
  __shared__ int nodes_s[128];
  int tid = threadIdx.x, w = tid >> 6, lane = tid & 63;
  int b0 = blockIdx.x * 16;
  if (tid < 128) nodes_s[tid] = nodes[b0 * 8 + tid];
  fill_w(wslot, tiles + 4 * TILE_BYTES, tid);      // geW
  __syncthreads();
  for (int idx = tid; idx < 2048; idx += 256) {
    int row = idx >> 7, d = idx & 127;
    float m = 0.f;
    #pragma unroll
    for (int j = 0; j < 8; ++j)
      m += u2e[(size_t)nodes_s[row * 8 + j] * DD + d];
    m *= 0.125f;
    int off = ((row << 8) + (d << 1)) ^ ((row & 7) << 4);
    *(unsigned short*)(mean_s + off) = f2bf(m);
  }
  __syncthreads();
  int cb = lane & 15, rb = (lane >> 4) << 2;
  f32x4 acc[2] = {(f32x4)(0.f), (f32x4)(0.f)};
  #pragma unroll
  for (int kk = 0; kk < 4; ++kk) {
    bf16x8 a = ldfrag(mean_s, 0, kk, lane);
    #pragma unroll
    for (int nf = 0; nf < 2; ++nf) {
      bf16x8 b = ldfrag(wslot, w * 32 + nf * 16, kk, lane);
      acc[nf] = MFMA(a, b, acc[nf]);
    }
  }
  __syncthreads();
  fill_w(wslot, tiles + 5 * TILE_BYTES, tid);      // a1W[128:]
  #pragma unroll
  for (int nf = 0; nf < 2; ++nf) {
    int col = w * 32 + nf * 16 + cb;
    float gb2 = geb[col];
    #pragma unroll
    for (int j = 0; j < 4; ++j) {
      int row = rb + j;
      float v = fmaxf(acc[nf][j] + gb2, 0.f);
      int off = ((row << 8) + (col << 1)) ^ ((row & 7) << 4);
      *(unsigned short*)(g_s + off) = f2bf(v);
    }
  }
  __syncthreads();
  acc[0] = (f32x4)(0.f); acc[1] = (f32x4)(0.f);
  #pragma unroll
  for (int kk = 0; kk < 4; ++kk) {
    bf16x8 a = ldfrag(g_s, 0, kk, lane);
    #pragma unroll
    for (int nf = 0; nf < 2; ++nf) {
      bf16x8 b = ldfrag(wslot, w * 32 + nf * 16, kk, lane);
      acc[nf] = MFMA(a, b, acc[nf]);
    }
  }
  #pragma unroll
  for (int nf = 0; nf < 2; ++nf) {
    int col = w * 32 + nf * 16 + cb;
    float bb = a1b[col];
    #pragma unroll
    for (int j = 0; j < 4; ++j)
      gbv[(size_t)(b0 + rb + j) * DD + col] = acc[nf][j] + bb;
  }
}

// 64f x 32l wave-tile GEMM over K=128 (A,B swizzled LDS tiles)
__device__ inline void gemmWX(f32x4 acc[8], const char* Wt, const char* Xt,
                              int mfw, int nlw, int lane) {
  #pragma unroll
  for (int kk = 0; kk < 4; ++kk) {
    bf16x8 bf0 = ldfrag(Xt, nlw * 32, kk, lane);
    bf16x8 bf1 = ldfrag(Xt, nlw * 32 + 16, kk, lane);
    #pragma unroll
    for (int mf = 0; mf < 4; ++mf) {
      bf16x8 a = ldfrag(Wt, mfw * 64 + mf * 16, kk, lane);
      acc[mf * 2]     = MFMA(a, bf0, acc[mf * 2]);
      acc[mf * 2 + 1] = MFMA(a, bf1, acc[mf * 2 + 1]);
    }
  }
}

// ---------------- main: 4 weight tiles LDS-resident, 16 rows/block as 8 pairs ----------------
__global__ __launch_bounds__(512, 1) void main_kernel(
    const int* __restrict__ hu, const int* __restrict__ hr,
    const int* __restrict__ hlen,
    const float* __restrict__ v2e,
    const float* __restrict__ b2, const float* __restrict__ a2b,
    const float* __restrict__ a3W, const float* __restrict__ a3b,
    const char* __restrict__ tiles, const float* __restrict__ Rp,
    const float* __restrict__ gbv, float* __restrict__ out) {
  __shared__ char smem[163840];          // full LDS pool
  char* W1s = smem;                      // 32768 (resident)
  char* W2s = smem + 32768;              // 32768 (resident)
  char* A1s = smem + 65536;              // 32768 (resident)
  char* A2s = smem + 98304;              // 32768 (resident)
  char* XA  = smem + 131072;             // 16384 (row A: x -> o -> a1 -> tail scratch)
  char* XB  = smem + 147456;             // 16384 (row B)

  const int tid = threadIdx.x, lane = tid & 63;
  const int wv = tid >> 6;
  const int rowsel = wv >> 2;              // 0: row A, 1: row B
  const int w4 = wv & 3;
  const int mfw = w4 >> 1, nlw = w4 & 1;   // 64f x 32l wave tile
  const int cb = lane & 15, g = lane >> 4;
  char* X = rowsel ? XB : XA;

  // ---- prologue: resident weight fills (once per block) ----
  #pragma unroll
  for (int i = 0; i < 4; ++i) {
    int ofs = (i * 8 + wv) << 10;          // 8 waves x 4 sweeps x 1 KB per tile
    async16(W1s + ofs, tiles + ofs + lane * 16);
    async16(W2s + ofs, tiles + TILE_BYTES + ofs + lane * 16);
    async16(A1s + ofs, tiles + 2 * TILE_BYTES + ofs + lane * 16);
    async16(A2s + ofs, tiles + 3 * TILE_BYTES + ofs + lane * 16);
  }
  const float a3bv = a3b[0];

  const int l0 = nlw * 32 + cb, l1 = l0 + 16;
  const int rbase = blockIdx.x * 16;
  int r = rbase + rowsel;
  int hu0 = hu[r * 64 + l0], hu1 = hu[r * 64 + l1];
  int hr0 = hr[r * 64 + l0], hr1 = hr[r * 64 + l1];
  __syncthreads();                         // weights resident

  for (int p = 0; p < 8; ++p) {
    // next pair's history indices (cheap; hides index latency)
    int hu0n = 0, hu1n = 0, hr0n = 0, hr1n = 0;
    if (p < 7) {
      int rn = r + 2;
      hu0n = hu[rn * 64 + l0]; hu1n = hu[rn * 64 + l1];
      hr0n = hr[rn * 64 + l0]; hr1n = hr[rn * 64 + l1];
    }

    f32x4 acc[8];
    #pragma unroll
    for (int i = 0; i < 8; ++i) acc[i] = (f32x4)(0.f);

    // ---- G1: x = e_uv @ W1[:128]; B built directly from global v2e rows
    {
      const float* rp0 = v2e + (size_t)hu0 * DD;
      const float* rp1 = v2e + (size_t)hu1 * DD;
      #pragma unroll
      for (int kk = 0; kk < 4; ++kk) {
        bf16x8 bf0 = ldAg(rp0, kk, lane);
        bf16x8 bf1 = ldAg(rp1, kk, lane);
        #pragma unroll
        for (int mf = 0; mf < 4; ++mf) {
          bf16x8 a = ldfrag(W1s, mfw * 64 + mf * 16, kk, lane);
          acc[mf * 2]     = MFMA(a, bf0, acc[mf * 2]);
          acc[mf * 2 + 1] = MFMA(a, bf1, acc[mf * 2 + 1]);
        }
      }
    }
    // epi1: +R'[hr] (global, L2-hot), relu -> X
    #pragma unroll
    for (int mf = 0; mf < 4; ++mf) {
      int f0 = mfw * 64 + mf * 16 + g * 4;
      float4 r0 = *(const float4*)(Rp + hr0 * DD + f0);
      float4 r1 = *(const float4*)(Rp + hr1 * DD + f0);
      f32x4 v0 = acc[mf * 2], v1 = acc[mf * 2 + 1];
      uint2 p0 = pack4(fmaxf(v0[0] + r0.x, 0.f), fmaxf(v0[1] + r0.y, 0.f),
                       fmaxf(v0[2] + r0.z, 0.f), fmaxf(v0[3] + r0.w, 0.f));
      uint2 p1 = pack4(fmaxf(v1[0] + r1.x, 0.f), fmaxf(v1[1] + r1.y, 0.f),
                       fmaxf(v1[2] + r1.z, 0.f), fmaxf(v1[3] + r1.w, 0.f));
      int o0 = ((l0 << 8) + (f0 << 1)) ^ ((l0 & 7) << 4);
      int o1 = ((l1 << 8) + (f0 << 1)) ^ ((l1 & 7) << 4);
      *(uint2*)(X + o0) = p0;
      *(uint2*)(X + o1) = p1;
    }
    __syncthreads();                       // (1) x ready

    // ---- G2: o = relu(x @ W2 + b2)
    #pragma unroll
    for (int i = 0; i < 8; ++i) acc[i] = (f32x4)(0.f);
    gemmWX(acc, W2s, X, mfw, nlw, lane);
    __syncthreads();                       // (2) done reading x
    uint2 opk[8];
    #pragma unroll
    for (int mf = 0; mf < 4; ++mf) {
      int f0 = mfw * 64 + mf * 16 + g * 4;
      float4 bb = *(const float4*)(b2 + f0);
      f32x4 v0 = acc[mf * 2], v1 = acc[mf * 2 + 1];
      uint2 p0 = pack4(fmaxf(v0[0] + bb.x, 0.f), fmaxf(v0[1] + bb.y, 0.f),
                       fmaxf(v0[2] + bb.z, 0.f), fmaxf(v0[3] + bb.w, 0.f));
      uint2 p1 = pack4(fmaxf(v1[0] + bb.x, 0.f), fmaxf(v1[1] + bb.y, 0.f),
                       fmaxf(v1[2] + bb.z, 0.f), fmaxf(v1[3] + bb.w, 0.f));
      opk[mf * 2] = p0; opk[mf * 2 + 1] = p1;
      int o0 = ((l0 << 8) + (f0 << 1)) ^ ((l0 & 7) << 4);
      int o1 = ((l1 << 8) + (f0 << 1)) ^ ((l1 & 7) << 4);
      *(uint2*)(X + o0) = p0;
      *(uint2*)(X + o1) = p1;
    }
    __syncthreads();                       // (3) o ready

    // ---- G3: a1 = relu(o @ a1W[:128] + gb)
    #pragma unroll
    for (int i = 0; i < 8; ++i) acc[i] = (f32x4)(0.f);
    gemmWX(acc, A1s, X, mfw, nlw, lane);
    __syncthreads();                       // (4) done reading o
    #pragma unroll
    for (int mf = 0; mf < 4; ++mf) {
      int f0 = mfw * 64 + mf * 16 + g * 4;
      float4 gv = *(const float4*)(gbv + (size_t)r * DD + f0);
      f32x4 v0 = acc[mf * 2], v1 = acc[mf * 2 + 1];
      uint2 p0 = pack4(fmaxf(v0[0] + gv.x, 0.f), fmaxf(v0[1] + gv.y, 0.f),
                       fmaxf(v0[2] + gv.z, 0.f), fmaxf(v0[3] + gv.w, 0.f));
      uint2 p1 = pack4(fmaxf(v1[0] + gv.x, 0.f), fmaxf(v1[1] + gv.y, 0.f),
                       fmaxf(v1[2] + gv.z, 0.f), fmaxf(v1[3] + gv.w, 0.f));
      int o0 = ((l0 << 8) + (f0 << 1)) ^ ((l0 & 7) << 4);
      int o1 = ((l1 << 8) + (f0 << 1)) ^ ((l1 & 7) << 4);
      *(uint2*)(X + o0) = p0;
      *(uint2*)(X + o1) = p1;
    }
    __syncthreads();                       // (5) a1 ready

    // ---- G4: a2-pre = a1 @ a2W
    #pragma unroll
    for (int i = 0; i < 8; ++i) acc[i] = (f32x4)(0.f);
    gemmWX(acc, A2s, X, mfw, nlw, lane);
    __syncthreads();                       // (6) done reading a1; X = tail scratch

    // logits partials: relu + dot a3W, reduce over g-groups
    {
      float s0 = 0.f, s1 = 0.f;
      #pragma unroll
      for (int mf = 0; mf < 4; ++mf) {
        int f0 = mfw * 64 + mf * 16 + g * 4;
        float4 ab = *(const float4*)(a2b + f0);
        float4 aw = *(const float4*)(a3W + f0);
        f32x4 v0 = acc[mf * 2], v1 = acc[mf * 2 + 1];
        s0 = fmaf(fmaxf(v0[0] + ab.x, 0.f), aw.x, s0);
        s0 = fmaf(fmaxf(v0[1] + ab.y, 0.f), aw.y, s0);
        s0 = fmaf(fmaxf(v0[2] + ab.z, 0.f), aw.z, s0);
        s0 = fmaf(fmaxf(v0[3] + ab.w, 0.f), aw.w, s0);
        s1 = fmaf(fmaxf(v1[0] + ab.x, 0.f), aw.x, s1);
        s1 = fmaf(fmaxf(v1[1] + ab.y, 0.f), aw.y, s1);
        s1 = fmaf(fmaxf(v1[2] + ab.z, 0.f), aw.z, s1);
        s1 = fmaf(fmaxf(v1[3] + ab.w, 0.f), aw.w, s1);
      }
      s0 += __shfl_xor(s0, 16); s0 += __shfl_xor(s0, 32);
      s1 += __shfl_xor(s1, 16); s1 += __shfl_xor(s1, 32);
      if (g == 0) {                        // lpart[mfw][l] at X + mfw*256 + l*4
        *(float*)(X + mfw * 256 + l0 * 4) = s0;
        *(float*)(X + mfw * 256 + l1 * 4) = s1;
      }
    }
    __syncthreads();                       // (7) lpart ready

    // masked softmax (wave 0 -> row A, wave 4 -> row B)
    if (w4 == 0) {
      int l = lane;
      float lv = *(const float*)(X + l * 4) + *(const float*)(X + 256 + l * 4) + a3bv;
      int len = hlen[r] + 1;
      bool valid = l < len;
      if (!valid) lv = -1e30f;
      float m = lv;
      #pragma unroll
      for (int off = 32; off; off >>= 1) m = fmaxf(m, __shfl_xor(m, off));
      float pe = valid ? expf(lv - m) : 0.f;
      float s = pe;
      #pragma unroll
      for (int off = 32; off; off >>= 1) s += __shfl_xor(s, off);
      *(float*)(X + 512 + l * 4) = pe / s;
    }
    __syncthreads();                       // (8) att ready

    // out-reduce from register o copy
    {
      float att0 = *(const float*)(X + 512 + l0 * 4);
      float att1 = *(const float*)(X + 512 + l1 * 4);
      float pr[4][4];
      #pragma unroll
      for (int mf = 0; mf < 4; ++mf) {
        uint2 q0 = opk[mf * 2], q1 = opk[mf * 2 + 1];
        pr[mf][0] = att0 * __uint_as_float(q0.x << 16)
                  + att1 * __uint_as_float(q1.x << 16);
        pr[mf][1] = att0 * __uint_as_float(q0.x & 0xffff0000u)
                  + att1 * __uint_as_float(q1.x & 0xffff0000u);
        pr[mf][2] = att0 * __uint_as_float(q0.y << 16)
                  + att1 * __uint_as_float(q1.y << 16);
        pr[mf][3] = att0 * __uint_as_float(q0.y & 0xffff0000u)
                  + att1 * __uint_as_float(q1.y & 0xffff0000u);
      }
      #pragma unroll
      for (int m = 1; m < 16; m <<= 1) {
        #pragma unroll
        for (int mf = 0; mf < 4; ++mf) {
          pr[mf][0] += __shfl_xor(pr[mf][0], m);
          pr[mf][1] += __shfl_xor(pr[mf][1], m);
          pr[mf][2] += __shfl_xor(pr[mf][2], m);
          pr[mf][3] += __shfl_xor(pr[mf][3], m);
        }
      }
      if (cb == 0) {                       // red[nlw][f] at X + 1024 + nlw*512 + f*4
        #pragma unroll
        for (int mf = 0; mf < 4; ++mf) {
          int f0 = mfw * 64 + mf * 16 + g * 4;
          float* rd = (float*)(X + 1024 + nlw * 512);
          rd[f0 + 0] = pr[mf][0];
          rd[f0 + 1] = pr[mf][1];
          rd[f0 + 2] = pr[mf][2];
          rd[f0 + 3] = pr[mf][3];
        }
      }
    }
    __syncthreads();                       // (9) red ready

    if (tid < 128 || (tid >= 256 && tid < 384)) {
      int d = tid & 127;
      out[(size_t)r * DD + d] = *(const float*)(X + 1024 + d * 4)
                              + *(const float*)(X + 1536 + d * 4);
    }
    __syncthreads();                       // (10) X free for next pair

    hu0 = hu0n; hu1 = hu1n; hr0 = hr0n; hr1 = hr1n;
    r += 2;
  }
}

extern "C" void kernel_launch(void* const* d_in, const int* in_sizes, int n_in,
                              void* d_out, int out_size, void* d_ws, size_t ws_size,
                              hipStream_t stream) {
  const int*   nodes = (const int*)d_in[0];
  const int*   hu    = (const int*)d_in[1];
  const int*   hr    = (const int*)d_in[2];
  const int*   hlen  = (const int*)d_in[3];
  const float* v2e   = (const float*)d_in[4];
  const float* u2e   = (const float*)d_in[5];
  const float* r2e   = (const float*)d_in[6];
  const float* W1    = (const float*)d_in[7];
  const float* b1    = (const float*)d_in[8];
  const float* W2    = (const float*)d_in[9];
  const float* b2    = (const float*)d_in[10];
  const float* a1W   = (const float*)d_in[11];
  const float* a1b   = (const float*)d_in[12];
  const float* a2W   = (const float*)d_in[13];
  const float* a2b   = (const float*)d_in[14];
  const float* a3W   = (const float*)d_in[15];
  const float* a3b   = (const float*)d_in[16];
  const float* geW   = (const float*)d_in[17];
  const float* geb   = (const float*)d_in[18];
  float* out = (float*)d_out;

  unsigned short* wsw = (unsigned short*)d_ws;
  const char* tiles = (const char*)d_ws;
  float* Rp  = (float*)((char*)d_ws + WS_R_OFF);
  float* gbv = (float*)((char*)d_ws + WS_GB_OFF);

  prep_weights<<<49, 256, 0, stream>>>(W1, W2, a1W, a2W, geW, r2e, b1, wsw, Rp);
  prep_gb<<<256, 256, 0, stream>>>(nodes, u2e, geb, a1b, tiles, gbv);
  main_kernel<<<256, 512, 0, stream>>>(
      hu, hr, hlen, v2e, b2, a2b, a3W, a3b, tiles, Rp, gbv, out);
}